// Round 4
// baseline (476.164 us; speedup 1.0000x reference)
//
#include <hip/hip_runtime.h>

#define T_STEPS 128
#define CIN     16
#define HH      64
#define WW      64
#define COUT    64
#define HWSZ    (HH * WW)          // 4096
#define CHW     (COUT * HWSZ)      // 262144
#define XCHW    (CIN * HWSZ)       // 65536

// pass-1: one t, one 32x32 spatial tile, one 32-co half per 512-thread block.
#define TILE    32
#define HALO    34
#define LSTR    36                  // padded LDS row stride (floats)
#define PLANE   (HALO * LSTR)       // 1224 floats per ci
#define NSTAGE  (CIN * HALO * HALO) // 18496

__global__ __launch_bounds__(512, 4)
void spiking_conv_pass1(const float* __restrict__ x, const float* __restrict__ Wt,
                        const float* __restrict__ b, float* __restrict__ out) {
    __shared__ float xs[CIN * PLANE];   // 78336 B -> 2 blocks/CU, 16 waves/CU

    const int tid = threadIdx.x;        // 0..511
    const int t   = blockIdx.y;
    const int h0  = (blockIdx.x >> 1) * TILE;
    const int w0  = (blockIdx.x & 1) * TILE;
    const int co0 = blockIdx.z * 32;

    // opaque VGPR zero: forces weight loads onto the vector-VMEM (vmcnt) path
    int vz;
    asm volatile("v_mov_b32 %0, 0" : "=v"(vz));

    // ---- stage 16-ci tile (+halo, zero-padded); fully unrolled -> 37 loads in flight
    const float* xt = x + t * XCHW;
#pragma unroll
    for (int k = 0; k < 37; ++k) {
        int e = tid + k * 512;
        bool ok = (e < NSTAGE);
        int ci  = e / (HALO * HALO);
        int rem = e - ci * (HALO * HALO);
        int r   = rem / HALO;
        int c   = rem - r * HALO;
        int gh  = h0 - 1 + r;
        int gw  = w0 - 1 + c;
        float v = 0.f;
        if (ok && (unsigned)gh < HH && (unsigned)gw < WW)
            v = xt[ci * HWSZ + gh * WW + gw];
        if (ok) xs[ci * PLANE + r * LSTR + c] = v;
    }
    __syncthreads();

    // ---- compute: thread = 1x2 patch ----
    const int pr0 = tid >> 4;          // 0..31
    const int pc0 = (tid & 15) * 2;    // 0..30
    float* outt = out + t * CHW;

#pragma unroll 1
    for (int cog = 0; cog < 4; ++cog) {
        float acc[8][2];
#pragma unroll
        for (int j = 0; j < 8; ++j) { acc[j][0] = 0.f; acc[j][1] = 0.f; }

#pragma unroll 1
        for (int cib = 0; cib < 4; ++cib) {
            // x patches for 4 ci (lgkm, in-order): 24x ds_read_b64
            float xv[4][3][4];
#pragma unroll
            for (int ci4 = 0; ci4 < 4; ++ci4) {
                const int ci = cib * 4 + ci4;
#pragma unroll
                for (int dr = 0; dr < 3; ++dr) {
                    const float* row = &xs[ci * PLANE + (pr0 + dr) * LSTR + pc0];
                    float2 a  = *(const float2*)row;
                    float2 c2 = *(const float2*)(row + 2);
                    xv[ci4][dr][0] = a.x;  xv[ci4][dr][1] = a.y;
                    xv[ci4][dr][2] = c2.x; xv[ci4][dr][3] = c2.y;
                }
            }
            // weights per j: 36 floats = 9 aligned dwordx4 (vmcnt, in-order)
#pragma unroll
            for (int j = 0; j < 8; ++j) {
                const int co = co0 + cog * 8 + j;
                const float* wb = Wt + co * (CIN * 9) + cib * 36 + vz;
                float w[36];
#pragma unroll
                for (int q = 0; q < 9; ++q) {
                    float4 f = *(const float4*)(wb + q * 4);
                    w[q * 4 + 0] = f.x; w[q * 4 + 1] = f.y;
                    w[q * 4 + 2] = f.z; w[q * 4 + 3] = f.w;
                }
#pragma unroll
                for (int ci4 = 0; ci4 < 4; ++ci4)
#pragma unroll
                    for (int ky = 0; ky < 3; ++ky)
#pragma unroll
                        for (int kx = 0; kx < 3; ++kx) {
                            const float wv = w[ci4 * 9 + ky * 3 + kx];
                            acc[j][0] += wv * xv[ci4][ky][kx];
                            acc[j][1] += wv * xv[ci4][ky][kx + 1];
                        }
            }
        }

        // ---- epilogue: +bias, float2 stores ----
#pragma unroll
        for (int j = 0; j < 8; ++j) {
            const int co = co0 + cog * 8 + j;
            const float bias = b[co];
            float2 o;
            o.x = acc[j][0] + bias;
            o.y = acc[j][1] + bias;
            *(float2*)&outt[co * HWSZ + (h0 + pr0) * WW + (w0 + pc0)] = o;
        }
    }
}

// In-place scan; loads of batch k+1 issue BEFORE stores of batch k so the
// vmcnt FIFO wait for loads never drains pending stores.
__global__ __launch_bounds__(256)
void spiking_scan_pass2(float* __restrict__ io) {
    const int idx = blockIdx.x * 256 + threadIdx.x;   // 0..262143
    float* p = io + idx;
    float s = 0.f;
    float v[8], nv[8];
#pragma unroll
    for (int i = 0; i < 8; ++i) v[i] = p[i * CHW];
#pragma unroll 1
    for (int tb = 0; tb < 15; ++tb) {
#pragma unroll
        for (int i = 0; i < 8; ++i) nv[i] = p[((tb + 1) * 8 + i) * CHW];
        float o[8];
#pragma unroll
        for (int i = 0; i < 8; ++i) {
            s += v[i];
            const bool sp = (s >= 8.0f);
            o[i] = sp ? 1.0f : 0.0f;
            s = sp ? 0.0f : s;
            s = fmaxf(s, -1.0f);
        }
#pragma unroll
        for (int i = 0; i < 8; ++i) p[(tb * 8 + i) * CHW] = o[i];
#pragma unroll
        for (int i = 0; i < 8; ++i) v[i] = nv[i];
    }
#pragma unroll
    for (int i = 0; i < 8; ++i) {
        s += v[i];
        const bool sp = (s >= 8.0f);
        p[(120 + i) * CHW] = sp ? 1.0f : 0.0f;
        s = sp ? 0.0f : s;
        s = fmaxf(s, -1.0f);
    }
}

extern "C" void kernel_launch(void* const* d_in, const int* in_sizes, int n_in,
                              void* d_out, int out_size, void* d_ws, size_t ws_size,
                              hipStream_t stream) {
    const float* x = (const float*)d_in[0];   // [128,16,64,64]
    const float* W = (const float*)d_in[1];   // [64,16,3,3]
    const float* b = (const float*)d_in[2];   // [64]
    float* out = (float*)d_out;               // [128,64,64,64]

    dim3 g1(4, 128, 2);   // 4 spatial tiles x 128 t x 2 co-halves = 1024 blocks
    spiking_conv_pass1<<<g1, 512, 0, stream>>>(x, W, b, out);

    spiking_scan_pass2<<<CHW / 256, 256, 0, stream>>>(out);
}

// Round 5
// 335.978 us; speedup vs baseline: 1.4172x; 1.4172x over previous
//
#include <hip/hip_runtime.h>

#define T_STEPS 128
#define CIN     16
#define HH      64
#define WW      64
#define COUT    64
#define HWSZ    (HH * WW)          // 4096
#define CHW     (COUT * HWSZ)      // 262144
#define XCHW    (CIN * HWSZ)       // 65536

// pass-1: block = one t, 32x64 spatial half, 16-co quarter, 512 threads.
// Thread = 1x4 patch. x staged in 8-ci chunks; weights via scalar s_load.
#define TR      34                  // halo rows
#define TC      66                  // halo cols (full width + 2)
#define LSTR    68                  // padded row stride (floats): 272 B, 16B-aligned
#define PLANE   (TR * LSTR)         // 2312 floats per ci
#define NST     (8 * TR * TC)       // 17952 staged elements per chunk

__global__ __launch_bounds__(512, 4)
void spiking_conv_pass1(const float* __restrict__ x, const float* __restrict__ Wt,
                        const float* __restrict__ b, float* __restrict__ out) {
    __shared__ float xs[8 * PLANE];   // 73984 B -> 2 blocks/CU, 16 waves/CU

    const int tid  = threadIdx.x;     // 0..511
    const int t    = blockIdx.y;
    const int half = blockIdx.x & 1;  // 32-row half
    const int coq  = blockIdx.x >> 1; // 16-co quarter
    const int h0   = half * 32;
    const int co0  = coq * 16;

    const float* xt  = x + t * XCHW;
    float* outt      = out + t * CHW;
    const int pr0 = tid >> 4;          // 0..31 (row)
    const int pc0 = (tid & 15) * 4;    // 0..60 (col, float4-aligned)

    float acc[2][8][4];
#pragma unroll
    for (int g = 0; g < 2; ++g)
#pragma unroll
        for (int j = 0; j < 8; ++j)
#pragma unroll
            for (int p = 0; p < 4; ++p) acc[g][j][p] = 0.f;

#pragma unroll 1
    for (int chunk = 0; chunk < 2; ++chunk) {
        if (chunk) __syncthreads();     // xs reuse fence
        // ---- stage 8-ci chunk (+halo, zero-padded) ----
        for (int e = tid; e < NST; e += 512) {
            int ci  = e / (TR * TC);
            int rem = e - ci * (TR * TC);
            int r   = rem / TC;
            int c   = rem - r * TC;
            int gh  = h0 - 1 + r;
            int gw  = c - 1;
            float v = 0.f;
            if ((unsigned)gh < HH && (unsigned)gw < WW)
                v = xt[(chunk * 8 + ci) * HWSZ + gh * WW + gw];
            xs[ci * PLANE + r * LSTR + c] = v;
        }
        __syncthreads();

#pragma unroll 1
        for (int ci = 0; ci < 8; ++ci) {
            // x patch 3x6 (3x ds_read_b128 + 3x ds_read_b64, bank-balanced)
            float xv[3][6];
#pragma unroll
            for (int dr = 0; dr < 3; ++dr) {
                const float* row = &xs[ci * PLANE + (pr0 + dr) * LSTR + pc0];
                float4 a  = *(const float4*)row;
                float2 c2 = *(const float2*)(row + 4);
                xv[dr][0] = a.x;  xv[dr][1] = a.y;
                xv[dr][2] = a.z;  xv[dr][3] = a.w;
                xv[dr][4] = c2.x; xv[dr][5] = c2.y;
            }
#pragma unroll
            for (int cog = 0; cog < 2; ++cog) {
                // weights: block-uniform address -> s_load into SGPRs
                float w[72];
#pragma unroll
                for (int j = 0; j < 8; ++j)
#pragma unroll
                    for (int k = 0; k < 9; ++k)
                        w[j * 9 + k] = Wt[(co0 + cog * 8 + j) * (CIN * 9) +
                                          (chunk * 8 + ci) * 9 + k];
#pragma unroll
                for (int j = 0; j < 8; ++j)
#pragma unroll
                    for (int ky = 0; ky < 3; ++ky)
#pragma unroll
                        for (int kx = 0; kx < 3; ++kx) {
                            const float wv = w[j * 9 + ky * 3 + kx];
#pragma unroll
                            for (int p = 0; p < 4; ++p)
                                acc[cog][j][p] += wv * xv[ky][kx + p];
                        }
            }
        }
    }

    // ---- epilogue: +bias, float4 stores (16 lanes -> 256 B contiguous) ----
#pragma unroll
    for (int cog = 0; cog < 2; ++cog)
#pragma unroll
        for (int j = 0; j < 8; ++j) {
            const int co = co0 + cog * 8 + j;
            const float bias = b[co];
            float4 o;
            o.x = acc[cog][j][0] + bias;
            o.y = acc[cog][j][1] + bias;
            o.z = acc[cog][j][2] + bias;
            o.w = acc[cog][j][3] + bias;
            *(float4*)&outt[co * HWSZ + (h0 + pr0) * WW + pc0] = o;
        }
}

// In-place scan: float2 columns, 32-t batches, nontemporal (lines touched once).
typedef float v2f __attribute__((ext_vector_type(2)));

__global__ __launch_bounds__(256)
void spiking_scan_pass2(float* __restrict__ io) {
    const int idx = blockIdx.x * 256 + threadIdx.x;   // 0..131071
    v2f* p = (v2f*)io + idx;                          // column stride CHW/2
    float sx = 0.f, sy = 0.f;
#pragma unroll 1
    for (int tb = 0; tb < 4; ++tb) {
        v2f v[32];
#pragma unroll
        for (int i = 0; i < 32; ++i)
            v[i] = __builtin_nontemporal_load(&p[(size_t)(tb * 32 + i) * (CHW / 2)]);
#pragma unroll
        for (int i = 0; i < 32; ++i) {
            sx += v[i].x;
            bool spx = (sx >= 8.0f);
            v[i].x = spx ? 1.0f : 0.0f;
            sx = spx ? 0.0f : sx;
            sx = fmaxf(sx, -1.0f);
            sy += v[i].y;
            bool spy = (sy >= 8.0f);
            v[i].y = spy ? 1.0f : 0.0f;
            sy = spy ? 0.0f : sy;
            sy = fmaxf(sy, -1.0f);
        }
#pragma unroll
        for (int i = 0; i < 32; ++i)
            __builtin_nontemporal_store(v[i], &p[(size_t)(tb * 32 + i) * (CHW / 2)]);
    }
}

extern "C" void kernel_launch(void* const* d_in, const int* in_sizes, int n_in,
                              void* d_out, int out_size, void* d_ws, size_t ws_size,
                              hipStream_t stream) {
    const float* x = (const float*)d_in[0];   // [128,16,64,64]
    const float* W = (const float*)d_in[1];   // [64,16,3,3]
    const float* b = (const float*)d_in[2];   // [64]
    float* out = (float*)d_out;               // [128,64,64,64]

    dim3 g1(8, 128);   // (2 halves x 4 co-quarters) x 128 t = 1024 blocks
    spiking_conv_pass1<<<g1, 512, 0, stream>>>(x, W, b, out);

    spiking_scan_pass2<<<(CHW / 2) / 256, 256, 0, stream>>>(out);
}

// Round 6
// 309.134 us; speedup vs baseline: 1.5403x; 1.0868x over previous
//
#include <hip/hip_runtime.h>

#define T_STEPS 128
#define CIN     16
#define HH      64
#define WW      64
#define COUT    64
#define HWSZ    (HH * WW)          // 4096
#define CHW     (COUT * HWSZ)      // 262144
#define XCHW    (CIN * HWSZ)       // 65536

// pass-1: block = one t, 32x32 spatial tile, 16-co quarter; 512 threads.
// Wave-halves of the block own one 8-co group each (wave-uniform weights).
#define TILE    32
#define HALO    34
#define LSTR    36                  // padded LDS row stride (floats)
#define PLANE   (HALO * LSTR)       // 1224 floats per ci
#define NST     (CIN * HALO * HALO) // 18496 staged elements
#define WBLK    80                  // padded weight block per (cog,ci): 72 used

// ---- setup: transpose W[64][16][3][3] -> Wtr[(coq*2+cog)*16+ci][80] (j*9+k) ----
__global__ void transpose_w(const float* __restrict__ W, float* __restrict__ Wtr) {
    int e = blockIdx.x * 256 + threadIdx.x;     // 0..9215
    if (e >= COUT * CIN * 9) return;
    int co = e / (CIN * 9);
    int r  = e - co * (CIN * 9);
    int ci = r / 9;
    int k  = r - ci * 9;
    int coq = co >> 4, cog = (co >> 3) & 1, j = co & 7;
    Wtr[(((coq * 2 + cog) * CIN) + ci) * WBLK + j * 9 + k] = W[e];
}

__global__ __launch_bounds__(512, 4)
void spiking_conv_pass1(const float* __restrict__ x, const float* __restrict__ Wtr,
                        const float* __restrict__ b, float* __restrict__ out) {
    __shared__ float xs[CIN * PLANE];   // 78336 B -> 2 blocks/CU, 16 waves/CU

    const int tid = threadIdx.x;        // 0..511
    const int t   = blockIdx.y;
    const int h0  = (blockIdx.x >> 1) * TILE;
    const int w0  = (blockIdx.x & 1) * TILE;
    const int coq = blockIdx.z;

    // ---- stage all 16 ci (+halo, zero-padded) once ----
    const float* xt = x + t * XCHW;
    for (int e = tid; e < NST; e += 512) {
        int ci  = e / (HALO * HALO);
        int rem = e - ci * (HALO * HALO);
        int r   = rem / HALO;
        int c   = rem - r * HALO;
        int gh  = h0 - 1 + r;
        int gw  = w0 - 1 + c;
        float v = 0.f;
        if ((unsigned)gh < HH && (unsigned)gw < WW)
            v = xt[ci * HWSZ + gh * WW + gw];
        xs[ci * PLANE + r * LSTR + c] = v;
    }
    __syncthreads();

    // ---- compute: wave-half picks co-group; thread = 1x4 patch ----
    const int cog = __builtin_amdgcn_readfirstlane(tid >> 8);  // 0/1, wave-uniform
    const int sp  = tid & 255;
    const int pr0 = sp >> 3;           // 0..31
    const int pc0 = (sp & 7) * 4;      // 0..28
    const float* wbase = Wtr + (coq * 2 + cog) * (CIN * WBLK);
    float* outt = out + t * CHW;

    float acc[8][4];
#pragma unroll
    for (int j = 0; j < 8; ++j)
#pragma unroll
        for (int p = 0; p < 4; ++p) acc[j][p] = 0.f;

#pragma unroll 1
    for (int ci = 0; ci < CIN; ++ci) {
        // x patch 3x6: ds_read_b128 + ds_read_b64 per row (lgkm, in-order)
        float xv[3][6];
#pragma unroll
        for (int dr = 0; dr < 3; ++dr) {
            const float* row = &xs[ci * PLANE + (pr0 + dr) * LSTR + pc0];
            float4 a  = *(const float4*)row;
            float2 c2 = *(const float2*)(row + 4);
            xv[dr][0] = a.x;  xv[dr][1] = a.y;
            xv[dr][2] = a.z;  xv[dr][3] = a.w;
            xv[dr][4] = c2.x; xv[dr][5] = c2.y;
        }
        // weights in two 36-float halves: contiguous, 16B-aligned -> wide s_load
#pragma unroll
        for (int half = 0; half < 2; ++half) {
            float w[36];
#pragma unroll
            for (int i = 0; i < 36; ++i)
                w[i] = wbase[ci * WBLK + half * 36 + i];
#pragma unroll
            for (int jj = 0; jj < 4; ++jj) {
                const int j = half * 4 + jj;
#pragma unroll
                for (int ky = 0; ky < 3; ++ky)
#pragma unroll
                    for (int kx = 0; kx < 3; ++kx) {
                        const float wv = w[jj * 9 + ky * 3 + kx];
#pragma unroll
                        for (int p = 0; p < 4; ++p)
                            acc[j][p] += wv * xv[ky][kx + p];
                    }
            }
        }
    }

    // ---- epilogue: +bias, float4 stores ----
#pragma unroll
    for (int j = 0; j < 8; ++j) {
        const int co = coq * 16 + cog * 8 + j;
        const float bias = b[co];
        float4 o;
        o.x = acc[j][0] + bias;
        o.y = acc[j][1] + bias;
        o.z = acc[j][2] + bias;
        o.w = acc[j][3] + bias;
        *(float4*)&outt[co * HWSZ + (h0 + pr0) * WW + (w0 + pc0)] = o;
    }
}

// In-place scan: scalar columns, batch-16, next-batch loads issued before
// current stores (R4's best-performing variant, widened).
__global__ __launch_bounds__(256)
void spiking_scan_pass2(float* __restrict__ io) {
    const int idx = blockIdx.x * 256 + threadIdx.x;   // 0..262143
    float* p = io + idx;
    float s = 0.f;
    float v[16], nv[16];
#pragma unroll
    for (int i = 0; i < 16; ++i) v[i] = p[i * CHW];
#pragma unroll 1
    for (int tb = 0; tb < 7; ++tb) {
#pragma unroll
        for (int i = 0; i < 16; ++i) nv[i] = p[((tb + 1) * 16 + i) * CHW];
        float o[16];
#pragma unroll
        for (int i = 0; i < 16; ++i) {
            s += v[i];
            const bool sp = (s >= 8.0f);
            o[i] = sp ? 1.0f : 0.0f;
            s = sp ? 0.0f : s;
            s = fmaxf(s, -1.0f);
        }
#pragma unroll
        for (int i = 0; i < 16; ++i) p[(tb * 16 + i) * CHW] = o[i];
#pragma unroll
        for (int i = 0; i < 16; ++i) v[i] = nv[i];
    }
#pragma unroll
    for (int i = 0; i < 16; ++i) {
        s += v[i];
        const bool sp = (s >= 8.0f);
        p[(112 + i) * CHW] = sp ? 1.0f : 0.0f;
        s = sp ? 0.0f : s;
        s = fmaxf(s, -1.0f);
    }
}

extern "C" void kernel_launch(void* const* d_in, const int* in_sizes, int n_in,
                              void* d_out, int out_size, void* d_ws, size_t ws_size,
                              hipStream_t stream) {
    const float* x = (const float*)d_in[0];   // [128,16,64,64]
    const float* W = (const float*)d_in[1];   // [64,16,3,3]
    const float* b = (const float*)d_in[2];   // [64]
    float* out = (float*)d_out;               // [128,64,64,64]
    float* Wtr = (float*)d_ws;                // 4*2*16*80*4 = 40960 B

    transpose_w<<<36, 256, 0, stream>>>(W, Wtr);

    dim3 g1(4, 128, 4);   // 4 spatial tiles x 128 t x 4 co-quarters = 2048 blocks
    spiking_conv_pass1<<<g1, 512, 0, stream>>>(x, Wtr, b, out);

    spiking_scan_pass2<<<CHW / 256, 256, 0, stream>>>(out);
}

// Round 7
// 263.872 us; speedup vs baseline: 1.8045x; 1.1715x over previous
//
#include <hip/hip_runtime.h>

#define T_STEPS 128
#define CIN     16
#define HH      64
#define WW      64
#define COUT    64
#define HWSZ    (HH * WW)          // 4096
#define CHW     (COUT * HWSZ)      // 262144
#define XCHW    (CIN * HWSZ)       // 65536

// pass-1: block = one t, 32x32 tile, 32-co half; wave-halves own 16 co each.
#define TILE    32
#define HALO    34
#define LSTR    36                  // padded LDS row stride (floats)
#define PLANE   (HALO * LSTR)       // 1224 floats per ci
#define NST     (CIN * HALO * HALO) // 18496 staged elements
#define WBLK    40                  // padded weight block per (co-group-of-4, ci)

// ---- setup: W[64][16][3][3] -> Wtr[(co>>2)*16+ci][40], inner (co&3)*9+k ----
__global__ void transpose_w(const float* __restrict__ W, float* __restrict__ Wtr) {
    int e = blockIdx.x * 256 + threadIdx.x;     // 0..9215
    if (e >= COUT * CIN * 9) return;
    int co = e / (CIN * 9);
    int r  = e - co * (CIN * 9);
    int ci = r / 9;
    int k  = r - ci * 9;
    Wtr[((co >> 2) * CIN + ci) * WBLK + (co & 3) * 9 + k] = W[e];
}

__global__ __launch_bounds__(512, 4)
void spiking_conv_pass1(const float* __restrict__ x, const float* __restrict__ Wtr,
                        const float* __restrict__ b, float* __restrict__ out) {
    __shared__ float xs[CIN * PLANE];   // 78336 B -> 2 blocks/CU, 16 waves/CU

    const int tid = threadIdx.x;        // 0..511
    const int t   = blockIdx.y;
    const int h0  = (blockIdx.x >> 1) * TILE;
    const int w0  = (blockIdx.x & 1) * TILE;
    const int coh = blockIdx.z;         // 0/1: 32-co half

    // ---- stage all 16 ci (+halo); two unrolled load-batches, loads in flight ----
    const float* xt = x + t * XCHW;
    {
        float vbuf[19]; int ibuf[19];
#pragma unroll
        for (int k = 0; k < 18; ++k) {
            unsigned e = tid + k * 512;
            unsigned ci = e / (HALO * HALO);
            unsigned rem = e - ci * (HALO * HALO);
            unsigned r  = rem / HALO;
            unsigned c  = rem - r * HALO;
            int gh = h0 - 1 + (int)r;
            int gw = w0 - 1 + (int)c;
            bool inb = (unsigned)gh < HH && (unsigned)gw < WW;
            vbuf[k] = inb ? xt[ci * HWSZ + gh * WW + gw] : 0.f;
            ibuf[k] = ci * PLANE + r * LSTR + c;
        }
#pragma unroll
        for (int k = 0; k < 18; ++k) xs[ibuf[k]] = vbuf[k];
#pragma unroll
        for (int k = 0; k < 19; ++k) {
            unsigned e = tid + (18 + k) * 512;
            unsigned ci = e / (HALO * HALO);
            unsigned rem = e - ci * (HALO * HALO);
            unsigned r  = rem / HALO;
            unsigned c  = rem - r * HALO;
            int gh = h0 - 1 + (int)r;
            int gw = w0 - 1 + (int)c;
            bool inb = e < NST && (unsigned)gh < HH && (unsigned)gw < WW;
            vbuf[k] = inb ? xt[ci * HWSZ + gh * WW + gw] : 0.f;
            ibuf[k] = (e < NST) ? (int)(ci * PLANE + r * LSTR + c) : -1;
        }
#pragma unroll
        for (int k = 0; k < 19; ++k)
            if (ibuf[k] >= 0) xs[ibuf[k]] = vbuf[k];
    }
    __syncthreads();

    // ---- compute: wave-half picks 16-co group; thread = 1x4 patch ----
    const int cog = __builtin_amdgcn_readfirstlane(tid >> 8);  // 0/1
    const int sp  = tid & 255;
    const int pr0 = sp >> 3;           // 0..31
    const int pc0 = (sp & 7) * 4;      // 0..28
    float* outt = out + t * CHW;

    float acc[16][4];
#pragma unroll
    for (int j = 0; j < 16; ++j)
#pragma unroll
        for (int p = 0; p < 4; ++p) acc[j][p] = 0.f;

#pragma unroll 1
    for (int ci = 0; ci < CIN; ++ci) {
        // x patch 3x6: ds_read_b128 + ds_read_b64 per row
        float xv[3][6];
#pragma unroll
        for (int dr = 0; dr < 3; ++dr) {
            const float* row = &xs[ci * PLANE + (pr0 + dr) * LSTR + pc0];
            float4 a  = *(const float4*)row;
            float2 c2 = *(const float2*)(row + 4);
            xv[dr][0] = a.x;  xv[dr][1] = a.y;
            xv[dr][2] = a.z;  xv[dr][3] = a.w;
            xv[dr][4] = c2.x; xv[dr][5] = c2.y;
        }
        // 4 co-groups of 4: contiguous 36-float scalar loads (wide s_load)
#pragma unroll
        for (int g = 0; g < 4; ++g) {
            const int g4 = coh * 8 + cog * 4 + g;          // block-uniform
            const float* wb = Wtr + (g4 * CIN + ci) * WBLK;
            float w[36];
#pragma unroll
            for (int i = 0; i < 36; ++i) w[i] = wb[i];
#pragma unroll
            for (int jj = 0; jj < 4; ++jj)
#pragma unroll
                for (int ky = 0; ky < 3; ++ky)
#pragma unroll
                    for (int kx = 0; kx < 3; ++kx) {
                        const float wv = w[jj * 9 + ky * 3 + kx];
#pragma unroll
                        for (int p = 0; p < 4; ++p)
                            acc[g * 4 + jj][p] += wv * xv[ky][kx + p];
                    }
        }
    }

    // ---- epilogue: +bias, float4 stores ----
#pragma unroll
    for (int g = 0; g < 4; ++g)
#pragma unroll
        for (int jj = 0; jj < 4; ++jj) {
            const int co = coh * 32 + cog * 16 + g * 4 + jj;
            const float bias = b[co];
            float4 o;
            o.x = acc[g * 4 + jj][0] + bias;
            o.y = acc[g * 4 + jj][1] + bias;
            o.z = acc[g * 4 + jj][2] + bias;
            o.w = acc[g * 4 + jj][3] + bias;
            *(float4*)&outt[co * HWSZ + (h0 + pr0) * WW + (w0 + pc0)] = o;
        }
}

// In-place scan: float4 columns (1KB contiguous per wave-load -> DRAM-row
// friendly), batch-8, next-batch loads issued before current stores.
__global__ __launch_bounds__(256)
void spiking_scan_pass2(float* __restrict__ io) {
    const int idx = blockIdx.x * 256 + threadIdx.x;   // 0..65535
    float4* p = (float4*)io + idx;                    // column stride CHW/4
    float sx = 0.f, sy = 0.f, sz = 0.f, sw = 0.f;
    float4 v[8], nv[8];
#pragma unroll
    for (int i = 0; i < 8; ++i) v[i] = p[(size_t)i * (CHW / 4)];
#pragma unroll 1
    for (int tb = 0; tb < 15; ++tb) {
#pragma unroll
        for (int i = 0; i < 8; ++i) nv[i] = p[(size_t)((tb + 1) * 8 + i) * (CHW / 4)];
#pragma unroll
        for (int i = 0; i < 8; ++i) {
            float4 o;
            sx += v[i].x; bool a0 = (sx >= 8.0f); o.x = a0 ? 1.f : 0.f; sx = a0 ? 0.f : sx; sx = fmaxf(sx, -1.f);
            sy += v[i].y; bool a1 = (sy >= 8.0f); o.y = a1 ? 1.f : 0.f; sy = a1 ? 0.f : sy; sy = fmaxf(sy, -1.f);
            sz += v[i].z; bool a2 = (sz >= 8.0f); o.z = a2 ? 1.f : 0.f; sz = a2 ? 0.f : sz; sz = fmaxf(sz, -1.f);
            sw += v[i].w; bool a3 = (sw >= 8.0f); o.w = a3 ? 1.f : 0.f; sw = a3 ? 0.f : sw; sw = fmaxf(sw, -1.f);
            p[(size_t)(tb * 8 + i) * (CHW / 4)] = o;
        }
#pragma unroll
        for (int i = 0; i < 8; ++i) v[i] = nv[i];
    }
#pragma unroll
    for (int i = 0; i < 8; ++i) {
        float4 o;
        sx += v[i].x; bool a0 = (sx >= 8.0f); o.x = a0 ? 1.f : 0.f; sx = a0 ? 0.f : sx; sx = fmaxf(sx, -1.f);
        sy += v[i].y; bool a1 = (sy >= 8.0f); o.y = a1 ? 1.f : 0.f; sy = a1 ? 0.f : sy; sy = fmaxf(sy, -1.f);
        sz += v[i].z; bool a2 = (sz >= 8.0f); o.z = a2 ? 1.f : 0.f; sz = a2 ? 0.f : sz; sz = fmaxf(sz, -1.f);
        sw += v[i].w; bool a3 = (sw >= 8.0f); o.w = a3 ? 1.f : 0.f; sw = a3 ? 0.f : sw; sw = fmaxf(sw, -1.f);
        p[(size_t)(120 + i) * (CHW / 4)] = o;
    }
}

extern "C" void kernel_launch(void* const* d_in, const int* in_sizes, int n_in,
                              void* d_out, int out_size, void* d_ws, size_t ws_size,
                              hipStream_t stream) {
    const float* x = (const float*)d_in[0];   // [128,16,64,64]
    const float* W = (const float*)d_in[1];   // [64,16,3,3]
    const float* b = (const float*)d_in[2];   // [64]
    float* out = (float*)d_out;               // [128,64,64,64]
    float* Wtr = (float*)d_ws;                // 16*16*40*4 = 40960 B

    transpose_w<<<36, 256, 0, stream>>>(W, Wtr);

    dim3 g1(4, 128, 2);   // 4 tiles x 128 t x 2 co-halves = 1024 blocks
    spiking_conv_pass1<<<g1, 512, 0, stream>>>(x, Wtr, b, out);

    spiking_scan_pass2<<<(CHW / 4) / 256, 256, 0, stream>>>(out);
}